// Round 14
// baseline (119.552 us; speedup 1.0000x reference)
//
#include <hip/hip_runtime.h>

typedef short short8 __attribute__((ext_vector_type(8)));
typedef float f32x4 __attribute__((ext_vector_type(4)));
typedef unsigned int u32;
typedef u32 u32x4 __attribute__((ext_vector_type(4)));
typedef unsigned short u16;

#define BB 32
#define LL 8192
#define TE 256
#define MM 33
#define INVL (1.0f/8192.0f)

// ---- ws float offsets ----
#define TBLM_OFF 0               // Tb bf16 [8192][64]
#define TTD_OFF  262144          // Tt bf16 [64][8192] (slot rows only)
#define VTB_OFF  589824          // Vtb bf16 [32][64][128] (V^T for k_main)
#define DD_OFF   720896          // f32 [32][64]  (M2-branch bias)
#define DD2_OFF  722944          // f32 [32][64]  (cos0 spectral bias)
#define BNP_OFF  731200          // f32 [32][2][64] per-batch BN partials

// ---- d_out (scr) float offsets; all dead before k_main overwrites ----
#define SRED2_OFF 4227072        // f32 [b][129][64] atomically accumulated
#define VF_OFF    4491264        // f32 V [b][128][64] (k-major, for k_bn)

static __device__ __forceinline__ u16 f2b(float f) {
  u32 u = __float_as_uint(f);
  return (u16)((u + 0x7FFFu + ((u >> 16) & 1u)) >> 16);   // RNE f32->bf16
}
// pack two floats -> (lo,hi) bf16 pair in one u32 via v_perm (half-up)
static __device__ __forceinline__ u32 pk2(float lo, float hi) {
  return __builtin_amdgcn_perm(__float_as_uint(hi) + 0x8000u,
                               __float_as_uint(lo) + 0x8000u,
                               0x07060302u);
}
// HW trig: input in revolutions, already reduced to [0,1)
static __device__ __forceinline__ float fsin(float rev) {
  float r; asm("v_sin_f32 %0, %1" : "=v"(r) : "v"(rev)); return r;
}
static __device__ __forceinline__ float fcos(float rev) {
  float r; asm("v_cos_f32 %0, %1" : "=v"(r) : "v"(rev)); return r;
}

// slot convention (j in 0..63): j=0: sin(m=32); j=1..32: cos(m=j); j=33..63: sin(m=j-32)

// ---------------------------------------------------------------------------
// blocks 0..1023: Tt[j][l]; 1024..2047: Tb[l][j]; 2048..2305: zero SRED2.
__global__ __launch_bounds__(256) void k_tbl(float* __restrict__ ws,
                                             float* __restrict__ scr) {
  int bid = blockIdx.x, tid = threadIdx.x;
  if (bid < 1024) {
    u16* tt = (u16*)ws + TTD_OFF * 2;
    int t = bid * 256 + tid;                  // < 8192*32
    int m = (t >> 13) + 1, l = t & (LL - 1);
    float rev = (float)((m * l) & (LL - 1)) * INVL;
    int js = (m == 32) ? 0 : 32 + m;
    tt[m * LL + l]  = f2b(fcos(rev));
    tt[js * LL + l] = f2b(fsin(rev));
  } else if (bid < 2048) {
    u16* tb = (u16*)ws;                       // TBLM_OFF = 0
    int t = (bid - 1024) * 256 + tid;         // < 8192*32
    int l = t >> 5, m = (t & 31) + 1;
    float rev = (float)((m * l) & (LL - 1)) * INVL;
    int js = (m == 32) ? 0 : 32 + m;
    tb[l * 64 + m]  = f2b(fcos(rev));
    tb[l * 64 + js] = f2b(fsin(rev));
  } else {
    // zero SRED2: 32*129*64 = 264192 floats = 66048 float4 = 258 blocks
    int t = (bid - 2048) * 256 + tid;
    float4* z = (float4*)(scr + SRED2_OFF);
    z[t] = make_float4(0.f, 0.f, 0.f, 0.f);
  }
}

// ---------------------------------------------------------------------------
// Phase A: DFT slot partials (rows 0..63) + ones row (64, VALU) + Gram rows
// (65..128) via MFMA; f32 atomicAdd accumulation into SRED2 (no PART pass).
// 1024 blocks x 512 (8 waves): w0..3 slot, w4..7 Gram.
__global__ __launch_bounds__(512) void k_dft(const float* __restrict__ x,
                                             const float* __restrict__ ws,
                                             float* __restrict__ scr) {
  __shared__ __align__(16) u16 sX[2][64 * 136];   // [ch][l'] bf16, 272B rows
  __shared__ float sOnes[8 * 64];
  int tid = threadIdx.x;
  int b = blockIdx.x >> 5, chunk = blockIdx.x & 31;
  int l0 = chunk * 256;
  int w = tid >> 6, lane = tid & 63;
  const u16* tt = (const u16*)ws + TTD_OFF * 2;

  f32x4 acc[4];
#pragma unroll
  for (int ct = 0; ct < 4; ++ct) acc[ct] = (f32x4){0.f, 0.f, 0.f, 0.f};

  int arow = lane & 15;
  int kb = (lane >> 4) * 8;                       // u16 units
  bool isg = (w >= 4);
  int gi = w - 4;
  int sc = tid & 63, lg = tid >> 6;               // staging: channel, l-group

  float vx[16];
  float psum = 0.f;
#pragma unroll
  for (int i = 0; i < 16; ++i)
    vx[i] = x[(b * LL + l0 + lg * 16 + i) * 64 + sc];
  {
    u32 wv[8];
#pragma unroll
    for (int j = 0; j < 8; ++j) {
      wv[j] = pk2(vx[2 * j], vx[2 * j + 1]);
      psum += vx[2 * j] + vx[2 * j + 1];
    }
    u32x4* dst = (u32x4*)&sX[0][sc * 136 + lg * 16];
    dst[0] = (u32x4){wv[0], wv[1], wv[2], wv[3]};
    dst[1] = (u32x4){wv[4], wv[5], wv[6], wv[7]};
  }
  __syncthreads();

#pragma unroll
  for (int i = 0; i < 16; ++i)
    vx[i] = x[(b * LL + l0 + 128 + lg * 16 + i) * 64 + sc];

#pragma unroll
  for (int kk = 0; kk < 4; ++kk) {
    short8 a = isg
      ? *reinterpret_cast<const short8*>(&sX[0][(gi * 16 + arow) * 136 + kk * 32 + kb])
      : *reinterpret_cast<const short8*>(tt + (w * 16 + arow) * LL + l0 + kk * 32 + kb);
#pragma unroll
    for (int ct = 0; ct < 4; ++ct) {
      short8 bf = *reinterpret_cast<const short8*>(&sX[0][(ct * 16 + arow) * 136 + kk * 32 + kb]);
      acc[ct] = __builtin_amdgcn_mfma_f32_16x16x32_bf16(a, bf, acc[ct], 0, 0, 0);
    }
  }

  {
    u32 wv[8];
#pragma unroll
    for (int j = 0; j < 8; ++j) {
      wv[j] = pk2(vx[2 * j], vx[2 * j + 1]);
      psum += vx[2 * j] + vx[2 * j + 1];
    }
    u32x4* dst = (u32x4*)&sX[1][sc * 136 + lg * 16];
    dst[0] = (u32x4){wv[0], wv[1], wv[2], wv[3]};
    dst[1] = (u32x4){wv[4], wv[5], wv[6], wv[7]};
  }
  sOnes[tid] = psum;
  __syncthreads();

#pragma unroll
  for (int kk = 0; kk < 4; ++kk) {
    short8 a = isg
      ? *reinterpret_cast<const short8*>(&sX[1][(gi * 16 + arow) * 136 + kk * 32 + kb])
      : *reinterpret_cast<const short8*>(tt + (w * 16 + arow) * LL + l0 + 128 + kk * 32 + kb);
#pragma unroll
    for (int ct = 0; ct < 4; ++ct) {
      short8 bf = *reinterpret_cast<const short8*>(&sX[1][(ct * 16 + arow) * 136 + kk * 32 + kb]);
      acc[ct] = __builtin_amdgcn_mfma_f32_16x16x32_bf16(a, bf, acc[ct], 0, 0, 0);
    }
  }

  // ---- accumulate into SRED2 (f32 atomics; device scope) ----
  int rowbase = isg ? (65 + gi * 16) : (w * 16);
  int rowb = (lane >> 4) * 4;
  float* sr2 = scr + SRED2_OFF + b * 8256;
#pragma unroll
  for (int ct = 0; ct < 4; ++ct) {
    int col = ct * 16 + (lane & 15);
#pragma unroll
    for (int r = 0; r < 4; ++r)
      atomicAdd(&sr2[(rowbase + rowb + r) * 64 + col], acc[ct][r]);
  }
  if (tid < 64) {
    float s = 0.f;
#pragma unroll
    for (int g = 0; g < 8; ++g) s += sOnes[g * 64 + tid];
    atomicAdd(&sr2[64 * 64 + tid], s);
  }
}

// ---------------------------------------------------------------------------
// Fused V-builder: blocks 0..32 = spectral mode m (with local t_c),
// blocks 33..64 = M2 for batch b (with local psi).  65 blocks x 256.
__global__ __launch_bounds__(256) void k_vb(
    const float* __restrict__ t_emb, const float* __restrict__ dre,
    const float* __restrict__ dim_, const float* __restrict__ pk,
    const float* __restrict__ swr, const float* __restrict__ swi,
    const float* __restrict__ ck, const float* __restrict__ cbias,
    const float* __restrict__ tw, float* __restrict__ scr,
    float* __restrict__ ws) {
  __shared__ float smem[12352];
  int tid = threadIdx.x;

  if (blockIdx.x < 33) {
    // ---------------- spectral path, mode m ----------------
    int m = blockIdx.x;
    float2* sW = (float2*)smem;                  // [4096]
    float2* sX = (float2*)(smem + 8192);         // [2048]
    float* sTcb = smem + 8192 + 4096;            // [64]

    for (int idx = tid; idx < 8192; idx += 256) smem[idx] = t_emb[idx];
    __syncthreads();
    if (tid < 64) {
      int b = tid & 31;
      const float* dd = (tid < 32) ? dre : dim_;
      float a = 0.f;
#pragma unroll 8
      for (int j = 0; j < TE; ++j) a = fmaf(smem[b * 256 + j], dd[j * MM + m], a);
      sTcb[tid] = a;
    }
    __syncthreads();

    for (int idx = tid; idx < 4096; idx += 256)
      sW[idx] = make_float2(swr[m * 4096 + idx], swi[m * 4096 + idx]);
    for (int idx = tid; idx < 2048; idx += 256) {
      int b = idx >> 6, i = idx & 63;
      const float* sr = scr + SRED2_OFF + b * 8256;
      float xr, xi;
      if (m == 0)      { xr = sr[64 * 64 + i] * INVL;  xi = 0.f; }
      else if (m < 32) { xr = sr[m * 64 + i] * INVL;   xi = -sr[(32 + m) * 64 + i] * INVL; }
      else             { xr = sr[32 * 64 + i] * INVL;  xi = -sr[0 * 64 + i] * INVL; }
      sX[idx] = make_float2(xr, xi);
    }
    __syncthreads();

    int w = tid >> 6, lane = tid & 63;
    for (int p = 0; p < 8; ++p) {
      int b = p * 4 + w;
      float a0 = 0.f, a1 = 0.f, a2 = 0.f, a3 = 0.f;
#pragma unroll 16
      for (int i = 0; i < 64; ++i) {
        float2 wv = sW[i * 64 + lane];
        float2 xv = sX[b * 64 + i];
        a0 = fmaf(xv.x, wv.x, a0);
        a1 = fmaf(xv.y, wv.y, a1);
        a2 = fmaf(xv.x, wv.y, a2);
        a3 = fmaf(xv.y, wv.x, a3);
      }
      float ar = a0 - a1, ai = a2 + a3;
      float tcr = sTcb[b], tci = sTcb[32 + b];
      float cr = tcr * ar - tci * ai;
      float ci = tcr * ai + tci * ar;
      if (m == 0) {
        ws[DD2_OFF + b * 64 + lane] = cr;
      } else {
        float crr = 2.f * cr, cii = -2.f * ci;
        int js = (m == 32) ? 0 : 32 + m;
        u16* vtb = (u16*)ws + VTB_OFF * 2 + (b * 64 + lane) * 128;
        vtb[64 + m] = f2b(crr);
        vtb[64 + js] = f2b(cii);
        float* vf = scr + VF_OFF + b * 8192;
        vf[(64 + m) * 64 + lane] = crr;
        vf[(64 + js) * 64 + lane] = cii;
      }
    }
  } else {
    // ---------------- M2 path, batch b ----------------
    int b = blockIdx.x - 33;
    float* sCkT = smem;              // [j][c] 4096
    float* sPtw = smem + 4096;       // [o][j] 4096
    float* sTe  = smem + 8192;       // [256]
    float* sPsi = smem + 8448;       // [128]

    sTe[tid] = t_emb[b * 256 + tid];
    __syncthreads();
    if (tid < 128) {
      float a = 0.f;
#pragma unroll 8
      for (int j = 0; j < TE; ++j) a = fmaf(sTe[j], pk[j * 128 + tid], a);
      sPsi[tid] = a;
    }
    __syncthreads();
    for (int idx = tid; idx < 4096; idx += 256) {
      int c = idx >> 6, j = idx & 63;
      sCkT[j * 64 + c] = ck[idx];
      sPtw[idx] = sPsi[j] * tw[idx];
    }
    __syncthreads();

    u16* vtb = (u16*)ws + VTB_OFF * 2 + b * 64 * 128;
    float* vf = scr + VF_OFF + b * 8192;
    int lane = tid & 63, w = tid >> 6;
#pragma unroll 4
    for (int it = 0; it < 16; ++it) {
      int o = it * 4 + w;
      float a = 0.f;
#pragma unroll 16
      for (int j = 0; j < 64; ++j)
        a = fmaf(sCkT[j * 64 + lane], sPtw[o * 64 + j], a);
      vtb[o * 128 + lane] = f2b(a);
      vf[lane * 64 + o] = a;
    }
    if (tid < 64) {
      float a = 0.f;
      for (int j = 0; j < 64; ++j) a = fmaf(cbias[j], sPtw[tid * 64 + j], a);
      ws[DD_OFF + b * 64 + tid] = a + sPsi[64 + tid];
    }
  }
}

// ---------------------------------------------------------------------------
// Analytic BN partials per batch (round-5 derivation).  32 blocks x 256.
__global__ __launch_bounds__(256) void k_bn(const float* __restrict__ scr,
                                            float* __restrict__ ws) {
  __shared__ float sVx[64 * 64];
  __shared__ float sGx[64 * 64];
  __shared__ float sS[64 * 64];
  __shared__ float sSum[64];
  __shared__ float sP[4][2][64];
  int tid = threadIdx.x, b = blockIdx.x;
  const float* sr = scr + SRED2_OFF + b * 8256;
  const float* vf = scr + VF_OFF + b * 8192;

  for (int p = tid; p < 4096; p += 256) {
    sVx[p] = vf[p];              // V rows 0..63
    sGx[p] = sr[65 * 64 + p];    // Gram rows
    sS[p]  = sr[p];              // slot rows 0..63
  }
  if (tid < 64) sSum[tid] = sr[64 * 64 + tid];
  __syncthreads();

  int o = tid & 63, part = tid >> 6;
  float m1 = 0.f, q1 = 0.f, cross = 0.f, vt2 = 0.f;
  for (int ii = 0; ii < 16; ++ii) {
    int i = part * 16 + ii;
    float vx = sVx[i * 64 + o];
    m1 = fmaf(sSum[i], vx, m1);
    float w0 = 0.f, w1 = 0.f, c0 = 0.f, c1 = 0.f;
#pragma unroll
    for (int j = 0; j < 64; j += 2) {
      float va = sVx[j * 64 + o], vb = sVx[(j + 1) * 64 + o];
      w0 = fmaf(sGx[i * 64 + j], va, w0);
      w1 = fmaf(sGx[i * 64 + j + 1], vb, w1);
      c0 = fmaf(sS[i * 64 + j], va, c0);
      c1 = fmaf(sS[i * 64 + j + 1], vb, c1);
    }
    q1 = fmaf(vx, w0 + w1, q1);
    float vt = vf[(64 + i) * 64 + o];
    vt2 = fmaf(vt, vt, vt2);
    cross = fmaf(vt, c0 + c1, cross);
  }
  sP[part][0][o] = m1;
  sP[part][1][o] = q1 + 2.f * cross + 4096.f * vt2;   // L/2 = 4096
  __syncthreads();
  if (tid < 64) {
    float m = sP[0][0][tid] + sP[1][0][tid] + sP[2][0][tid] + sP[3][0][tid];
    float q = sP[0][1][tid] + sP[1][1][tid] + sP[2][1][tid] + sP[3][1][tid];
    float D = ws[DD_OFF + b * 64 + tid] + ws[DD2_OFF + b * 64 + tid];
    ws[BNP_OFF + b * 128 + tid]      = m + 8192.f * D;
    ws[BNP_OFF + b * 128 + 64 + tid] = q + 2.f * D * m + 8192.f * D * D;
  }
}

// ---------------------------------------------------------------------------
// Phase C: out = relu(alpha*(U@V + D) + beta) via MFMA; B-fragments from
// global Vtb (L2-resident); in-block alpha/beta finalization.  2048 x 256.
__global__ __launch_bounds__(256) void k_main(const float* __restrict__ x,
                                              const float* __restrict__ ws,
                                              const float* __restrict__ bns,
                                              const float* __restrict__ bnb,
                                              float* __restrict__ out) {
  __shared__ float sD[64];
  __shared__ float sA[64];
  __shared__ float sB[64];
  __shared__ float sPp[4][64];
  __shared__ float sPq[4][64];
  int tid = threadIdx.x, w = tid >> 6, lane = tid & 63;
  int b = blockIdx.x >> 6, rg = blockIdx.x & 63;
  const u16* wsu = (const u16*)ws;

  int kb = (lane >> 4) * 8;
  const u16* vtb = wsu + VTB_OFF * 2 + b * 64 * 128;
  short8 bf[4][4];
#pragma unroll
  for (int kk = 0; kk < 4; ++kk)
#pragma unroll
    for (int ct = 0; ct < 4; ++ct)
      bf[kk][ct] = *reinterpret_cast<const short8*>(
          vtb + (ct * 16 + (lane & 15)) * 128 + kk * 32 + kb);

  {
    int o = tid & 63, g = tid >> 6;
    float pm = 0.f, pq = 0.f;
#pragma unroll
    for (int r = 0; r < 8; ++r) {
      int bb = g * 8 + r;
      pm += ws[BNP_OFF + bb * 128 + o];
      pq += ws[BNP_OFF + bb * 128 + 64 + o];
    }
    sPp[g][o] = pm;
    sPq[g][o] = pq;
  }
  if (tid < 64) sD[tid] = ws[DD_OFF + b * 64 + tid] + ws[DD2_OFF + b * 64 + tid];
  __syncthreads();
  if (tid < 64) {
    const float inv_n = 1.f / (32.f * 8192.f);
    float mean = (sPp[0][tid] + sPp[1][tid] + sPp[2][tid] + sPp[3][tid]) * inv_n;
    float ex2  = (sPq[0][tid] + sPq[1][tid] + sPq[2][tid] + sPq[3][tid]) * inv_n;
    float var = ex2 - mean * mean;
    float istd = rsqrtf(var + 1e-5f);
    float al = istd * bns[tid];
    sA[tid] = al;
    sB[tid] = bnb[tid] - mean * al;
  }
  __syncthreads();

  const u16* tb = wsu;                      // TBLM_OFF = 0
  int rowb = (lane >> 4) * 4;
  int lbase = rg * 128 + w * 32;

#pragma unroll
  for (int rt = 0; rt < 2; ++rt) {
    int l = lbase + rt * 16 + (lane & 15);
    const float* xq = x + (b * LL + l) * 64;
    float4 u0 = *reinterpret_cast<const float4*>(xq + kb);
    float4 u1 = *reinterpret_cast<const float4*>(xq + kb + 4);
    float4 u2 = *reinterpret_cast<const float4*>(xq + 32 + kb);
    float4 u3 = *reinterpret_cast<const float4*>(xq + 32 + kb + 4);
    union { short8 s; u32 wv[4]; } A0, A1;
    A0.wv[0] = pk2(u0.x, u0.y); A0.wv[1] = pk2(u0.z, u0.w);
    A0.wv[2] = pk2(u1.x, u1.y); A0.wv[3] = pk2(u1.z, u1.w);
    A1.wv[0] = pk2(u2.x, u2.y); A1.wv[1] = pk2(u2.z, u2.w);
    A1.wv[2] = pk2(u3.x, u3.y); A1.wv[3] = pk2(u3.z, u3.w);
    short8 a2 = *reinterpret_cast<const short8*>(tb + l * 64 + kb);
    short8 a3 = *reinterpret_cast<const short8*>(tb + l * 64 + 32 + kb);

    f32x4 acc[4];
#pragma unroll
    for (int ct = 0; ct < 4; ++ct) acc[ct] = (f32x4){0.f, 0.f, 0.f, 0.f};
#pragma unroll
    for (int ct = 0; ct < 4; ++ct) {
      acc[ct] = __builtin_amdgcn_mfma_f32_16x16x32_bf16(A0.s, bf[0][ct], acc[ct], 0, 0, 0);
      acc[ct] = __builtin_amdgcn_mfma_f32_16x16x32_bf16(A1.s, bf[1][ct], acc[ct], 0, 0, 0);
      acc[ct] = __builtin_amdgcn_mfma_f32_16x16x32_bf16(a2, bf[2][ct], acc[ct], 0, 0, 0);
      acc[ct] = __builtin_amdgcn_mfma_f32_16x16x32_bf16(a3, bf[3][ct], acc[ct], 0, 0, 0);
    }
#pragma unroll
    for (int ct = 0; ct < 4; ++ct) {
      int o = ct * 16 + (lane & 15);
      float dd = sD[o], al = sA[o], be = sB[o];
#pragma unroll
      for (int r = 0; r < 4; ++r) {
        float v = acc[ct][r] + dd;
        out[(b * LL + lbase + rt * 16 + rowb + r) * 64 + o] =
            fmaxf(fmaf(v, al, be), 0.f);
      }
    }
  }
}

// ---------------------------------------------------------------------------
extern "C" void kernel_launch(void* const* d_in, const int* in_sizes, int n_in,
                              void* d_out, int out_size, void* d_ws, size_t ws_size,
                              hipStream_t stream) {
  const float* x     = (const float*)d_in[0];
  const float* t_emb = (const float*)d_in[1];
  const float* swr   = (const float*)d_in[2];
  const float* swi   = (const float*)d_in[3];
  const float* dre   = (const float*)d_in[4];
  const float* dim_  = (const float*)d_in[5];
  const float* ck    = (const float*)d_in[6];
  const float* cbias = (const float*)d_in[7];
  const float* tw    = (const float*)d_in[8];
  const float* pk    = (const float*)d_in[9];
  const float* bns   = (const float*)d_in[10];
  const float* bnb   = (const float*)d_in[11];
  float* ws  = (float*)d_ws;
  float* out = (float*)d_out;

  k_tbl<<<2306, 256, 0, stream>>>(ws, out);             // tables + zero SRED2
  k_dft<<<1024, 512, 0, stream>>>(x, ws, out);          // atomic SRED2 accum
  k_vb<<<65, 256, 0, stream>>>(t_emb, dre, dim_, pk, swr, swi,
                               ck, cbias, tw, out, ws);
  k_bn<<<32, 256, 0, stream>>>(out, ws);
  k_main<<<2048, 256, 0, stream>>>(x, ws, bns, bnb, out); // overwrites d_out
}

// Round 15
// 90.657 us; speedup vs baseline: 1.3187x; 1.3187x over previous
//
#include <hip/hip_runtime.h>
#include <hip/hip_fp16.h>

typedef short short8 __attribute__((ext_vector_type(8)));
typedef float f32x4 __attribute__((ext_vector_type(4)));
typedef unsigned int u32;
typedef u32 u32x4 __attribute__((ext_vector_type(4)));
typedef unsigned short u16;

#define BB 32
#define LL 8192
#define TE 256
#define MM 33
#define INVL (1.0f/8192.0f)

// ---- ws float offsets ----
#define VTB_OFF  589824          // Vtb bf16 [32][64][128] (V^T for k_main)
#define DD_OFF   720896          // f32 [32][64]  (M2-branch bias)
#define DD2_OFF  722944          // f32 [32][64]  (cos0 spectral bias)
#define BNP_OFF  731200          // f32 [32][2][64] per-batch BN partials

// ---- d_out (scr) offsets; all dead before k_main overwrites ----
// PART: f16 [b][chunk32][129][64]  (rows 0..63 slots, 64 = ones, 65..128 Gram)
#define SRED2_OFF 4227072        // f32 [b][129][64] chunk-reduced (float offset)
#define VF_OFF    4491264        // f32 V [b][128][64] (k-major, for k_bn)

static __device__ __forceinline__ u16 f2b(float f) {
  u32 u = __float_as_uint(f);
  return (u16)((u + 0x7FFFu + ((u >> 16) & 1u)) >> 16);   // RNE f32->bf16
}
// pack two floats -> (lo,hi) bf16 pair in one u32 via v_perm (half-up)
static __device__ __forceinline__ u32 pk2(float lo, float hi) {
  return __builtin_amdgcn_perm(__float_as_uint(hi) + 0x8000u,
                               __float_as_uint(lo) + 0x8000u,
                               0x07060302u);
}
// HW trig: input in revolutions, already reduced to [0,1)
static __device__ __forceinline__ float fsin(float rev) {
  float r; asm("v_sin_f32 %0, %1" : "=v"(r) : "v"(rev)); return r;
}
static __device__ __forceinline__ float fcos(float rev) {
  float r; asm("v_cos_f32 %0, %1" : "=v"(r) : "v"(rev)); return r;
}
// slot convention (j in 0..63): j=0: sin(m=32); j=1..32: cos(m=j); j=33..63: sin(m=j-32)
static __device__ __forceinline__ u16 tval(int m, bool is_sin, int l) {
  float rev = (float)((m * l) & (LL - 1)) * INVL;
  return f2b(is_sin ? fsin(rev) : fcos(rev));
}
static __device__ __forceinline__ u16 tslotj(int j, int l) {
  int m = (j == 0) ? 32 : (j <= 32 ? j : j - 32);
  bool is_sin = (j == 0) || (j >= 33);
  return tval(m, is_sin, l);
}

// ---------------------------------------------------------------------------
// Phase A: DFT slot partials (rows 0..63, trig computed in-register) +
// ones row (64, VALU) + Gram rows (65..128) via MFMA.  f16 partials.
// 1024 blocks x 512 (8 waves): w0..3 slot, w4..7 Gram.
__global__ __launch_bounds__(512) void k_dft(const float* __restrict__ x,
                                             float* __restrict__ scr) {
  __shared__ __align__(16) u16 sX[2][64 * 136];   // [ch][l'] bf16, 272B rows
  __shared__ float sOnes[8 * 64];
  int tid = threadIdx.x;
  int b = blockIdx.x >> 5, chunk = blockIdx.x & 31;
  int l0 = chunk * 256;
  int w = tid >> 6, lane = tid & 63;

  f32x4 acc[4];
#pragma unroll
  for (int ct = 0; ct < 4; ++ct) acc[ct] = (f32x4){0.f, 0.f, 0.f, 0.f};

  int arow = lane & 15;
  int kb = (lane >> 4) * 8;                       // u16 units
  bool isg = (w >= 4);
  int gi = w - 4;
  int sc = tid & 63, lg = tid >> 6;               // staging: channel, l-group

  // per-lane slot row (slot waves only)
  int jrow = w * 16 + arow;
  int m_slot = (jrow == 0) ? 32 : (jrow <= 32 ? jrow : jrow - 32);
  bool is_sin = (jrow == 0) || (jrow >= 33);

  float vx[16];
  float psum = 0.f;
#pragma unroll
  for (int i = 0; i < 16; ++i)
    vx[i] = x[(b * LL + l0 + lg * 16 + i) * 64 + sc];
  {
    u32 wv[8];
#pragma unroll
    for (int j = 0; j < 8; ++j) {
      wv[j] = pk2(vx[2 * j], vx[2 * j + 1]);
      psum += vx[2 * j] + vx[2 * j + 1];
    }
    u32x4* dst = (u32x4*)&sX[0][sc * 136 + lg * 16];
    dst[0] = (u32x4){wv[0], wv[1], wv[2], wv[3]};
    dst[1] = (u32x4){wv[4], wv[5], wv[6], wv[7]};
  }
  __syncthreads();

#pragma unroll
  for (int i = 0; i < 16; ++i)
    vx[i] = x[(b * LL + l0 + 128 + lg * 16 + i) * 64 + sc];

#pragma unroll
  for (int kk = 0; kk < 4; ++kk) {
    short8 a;
    if (isg) {
      a = *reinterpret_cast<const short8*>(&sX[0][(gi * 16 + arow) * 136 + kk * 32 + kb]);
    } else {
      union { short8 s; u32 wv[4]; } A;
      int lb = l0 + kk * 32 + kb;
#pragma unroll
      for (int p2 = 0; p2 < 4; ++p2)
        A.wv[p2] = (u32)tval(m_slot, is_sin, lb + 2 * p2) |
                   ((u32)tval(m_slot, is_sin, lb + 2 * p2 + 1) << 16);
      a = A.s;
    }
#pragma unroll
    for (int ct = 0; ct < 4; ++ct) {
      short8 bf = *reinterpret_cast<const short8*>(&sX[0][(ct * 16 + arow) * 136 + kk * 32 + kb]);
      acc[ct] = __builtin_amdgcn_mfma_f32_16x16x32_bf16(a, bf, acc[ct], 0, 0, 0);
    }
  }

  {
    u32 wv[8];
#pragma unroll
    for (int j = 0; j < 8; ++j) {
      wv[j] = pk2(vx[2 * j], vx[2 * j + 1]);
      psum += vx[2 * j] + vx[2 * j + 1];
    }
    u32x4* dst = (u32x4*)&sX[1][sc * 136 + lg * 16];
    dst[0] = (u32x4){wv[0], wv[1], wv[2], wv[3]};
    dst[1] = (u32x4){wv[4], wv[5], wv[6], wv[7]};
  }
  sOnes[tid] = psum;
  __syncthreads();

#pragma unroll
  for (int kk = 0; kk < 4; ++kk) {
    short8 a;
    if (isg) {
      a = *reinterpret_cast<const short8*>(&sX[1][(gi * 16 + arow) * 136 + kk * 32 + kb]);
    } else {
      union { short8 s; u32 wv[4]; } A;
      int lb = l0 + 128 + kk * 32 + kb;
#pragma unroll
      for (int p2 = 0; p2 < 4; ++p2)
        A.wv[p2] = (u32)tval(m_slot, is_sin, lb + 2 * p2) |
                   ((u32)tval(m_slot, is_sin, lb + 2 * p2 + 1) << 16);
      a = A.s;
    }
#pragma unroll
    for (int ct = 0; ct < 4; ++ct) {
      short8 bf = *reinterpret_cast<const short8*>(&sX[1][(ct * 16 + arow) * 136 + kk * 32 + kb]);
      acc[ct] = __builtin_amdgcn_mfma_f32_16x16x32_bf16(a, bf, acc[ct], 0, 0, 0);
    }
  }

  int rowbase = isg ? (65 + gi * 16) : (w * 16);
  int rowb = (lane >> 4) * 4;
  u16* pp = (u16*)scr + (size_t)(b * 32 + chunk) * 129 * 64;
#pragma unroll
  for (int ct = 0; ct < 4; ++ct) {
    int col = ct * 16 + (lane & 15);
#pragma unroll
    for (int r = 0; r < 4; ++r)
      pp[(rowbase + rowb + r) * 64 + col] = __half_as_ushort(__float2half(acc[ct][r]));
  }
  if (tid < 64) {
    float s = 0.f;
#pragma unroll
    for (int g = 0; g < 8; ++g) s += sOnes[g * 64 + tid];
    pp[64 * 64 + tid] = __half_as_ushort(__float2half(s));
  }
}

// ---------------------------------------------------------------------------
// Reduce f16 partials over 32 chunks -> SRED2[b][129][64] f32.  544 blocks.
__global__ __launch_bounds__(256) void k_red1(float* __restrict__ scr) {
  int bid = blockIdx.x, tid = threadIdx.x;
  int b = bid / 17, rx = bid % 17;
  int p = rx * 256 + tid;                     // u32-pair index < 4128
  if (p >= 4128) return;
  const u32* pb = (const u32*)scr + (size_t)b * 32 * 4128;
  float a0 = 0.f, a1 = 0.f;
#pragma unroll 8
  for (int ch = 0; ch < 32; ++ch) {
    u32 u = pb[ch * 4128 + p];
    __half2 h2 = *reinterpret_cast<const __half2*>(&u);
    float2 f = __half22float2(h2);
    a0 += f.x; a1 += f.y;
  }
  *reinterpret_cast<float2*>(scr + SRED2_OFF + b * 8256 + 2 * p) =
      make_float2(a0, a1);
}

// ---------------------------------------------------------------------------
// Fused V-builder: blocks 0..32 = spectral mode m (with local t_c),
// blocks 33..64 = M2 for batch b (with local psi).  65 blocks x 256.
__global__ __launch_bounds__(256) void k_vb(
    const float* __restrict__ t_emb, const float* __restrict__ dre,
    const float* __restrict__ dim_, const float* __restrict__ pk,
    const float* __restrict__ swr, const float* __restrict__ swi,
    const float* __restrict__ ck, const float* __restrict__ cbias,
    const float* __restrict__ tw, float* __restrict__ scr,
    float* __restrict__ ws) {
  __shared__ float smem[12352];
  int tid = threadIdx.x;

  if (blockIdx.x < 33) {
    // ---------------- spectral path, mode m ----------------
    int m = blockIdx.x;
    float2* sW = (float2*)smem;                  // [4096]
    float2* sX = (float2*)(smem + 8192);         // [2048]
    float* sTcb = smem + 8192 + 4096;            // [64]

    for (int idx = tid; idx < 8192; idx += 256) smem[idx] = t_emb[idx];
    __syncthreads();
    if (tid < 64) {
      int b = tid & 31;
      const float* dd = (tid < 32) ? dre : dim_;
      float a = 0.f;
#pragma unroll 8
      for (int j = 0; j < TE; ++j) a = fmaf(smem[b * 256 + j], dd[j * MM + m], a);
      sTcb[tid] = a;
    }
    __syncthreads();

    for (int idx = tid; idx < 4096; idx += 256)
      sW[idx] = make_float2(swr[m * 4096 + idx], swi[m * 4096 + idx]);
    for (int idx = tid; idx < 2048; idx += 256) {
      int b = idx >> 6, i = idx & 63;
      const float* sr = scr + SRED2_OFF + b * 8256;
      float xr, xi;
      if (m == 0)      { xr = sr[64 * 64 + i] * INVL;  xi = 0.f; }
      else if (m < 32) { xr = sr[m * 64 + i] * INVL;   xi = -sr[(32 + m) * 64 + i] * INVL; }
      else             { xr = sr[32 * 64 + i] * INVL;  xi = -sr[0 * 64 + i] * INVL; }
      sX[idx] = make_float2(xr, xi);
    }
    __syncthreads();

    int w = tid >> 6, lane = tid & 63;
    for (int p = 0; p < 8; ++p) {
      int b = p * 4 + w;
      float a0 = 0.f, a1 = 0.f, a2 = 0.f, a3 = 0.f;
#pragma unroll 16
      for (int i = 0; i < 64; ++i) {
        float2 wv = sW[i * 64 + lane];
        float2 xv = sX[b * 64 + i];
        a0 = fmaf(xv.x, wv.x, a0);
        a1 = fmaf(xv.y, wv.y, a1);
        a2 = fmaf(xv.x, wv.y, a2);
        a3 = fmaf(xv.y, wv.x, a3);
      }
      float ar = a0 - a1, ai = a2 + a3;
      float tcr = sTcb[b], tci = sTcb[32 + b];
      float cr = tcr * ar - tci * ai;
      float ci = tcr * ai + tci * ar;
      if (m == 0) {
        ws[DD2_OFF + b * 64 + lane] = cr;
      } else {
        float crr = 2.f * cr, cii = -2.f * ci;
        int js = (m == 32) ? 0 : 32 + m;
        u16* vtb = (u16*)ws + VTB_OFF * 2 + (b * 64 + lane) * 128;
        vtb[64 + m] = f2b(crr);
        vtb[64 + js] = f2b(cii);
        float* vf = scr + VF_OFF + b * 8192;
        vf[(64 + m) * 64 + lane] = crr;
        vf[(64 + js) * 64 + lane] = cii;
      }
    }
  } else {
    // ---------------- M2 path, batch b ----------------
    int b = blockIdx.x - 33;
    float* sCkT = smem;              // [j][c] 4096
    float* sPtw = smem + 4096;       // [o][j] 4096
    float* sTe  = smem + 8192;       // [256]
    float* sPsi = smem + 8448;       // [128]

    sTe[tid] = t_emb[b * 256 + tid];
    __syncthreads();
    if (tid < 128) {
      float a = 0.f;
#pragma unroll 8
      for (int j = 0; j < TE; ++j) a = fmaf(sTe[j], pk[j * 128 + tid], a);
      sPsi[tid] = a;
    }
    __syncthreads();
    for (int idx = tid; idx < 4096; idx += 256) {
      int c = idx >> 6, j = idx & 63;
      sCkT[j * 64 + c] = ck[idx];
      sPtw[idx] = sPsi[j] * tw[idx];
    }
    __syncthreads();

    u16* vtb = (u16*)ws + VTB_OFF * 2 + b * 64 * 128;
    float* vf = scr + VF_OFF + b * 8192;
    int lane = tid & 63, w = tid >> 6;
#pragma unroll 4
    for (int it = 0; it < 16; ++it) {
      int o = it * 4 + w;
      float a = 0.f;
#pragma unroll 16
      for (int j = 0; j < 64; ++j)
        a = fmaf(sCkT[j * 64 + lane], sPtw[o * 64 + j], a);
      vtb[o * 128 + lane] = f2b(a);
      vf[lane * 64 + o] = a;
    }
    if (tid < 64) {
      float a = 0.f;
      for (int j = 0; j < 64; ++j) a = fmaf(cbias[j], sPtw[tid * 64 + j], a);
      ws[DD_OFF + b * 64 + tid] = a + sPsi[64 + tid];
    }
  }
}

// ---------------------------------------------------------------------------
// Analytic BN partials per batch (round-5 derivation).  32 blocks x 256.
__global__ __launch_bounds__(256) void k_bn(const float* __restrict__ scr,
                                            float* __restrict__ ws) {
  __shared__ float sVx[64 * 64];
  __shared__ float sGx[64 * 64];
  __shared__ float sS[64 * 64];
  __shared__ float sSum[64];
  __shared__ float sP[4][2][64];
  int tid = threadIdx.x, b = blockIdx.x;
  const float* sr = scr + SRED2_OFF + b * 8256;
  const float* vf = scr + VF_OFF + b * 8192;

  for (int p = tid; p < 4096; p += 256) {
    sVx[p] = vf[p];              // V rows 0..63
    sGx[p] = sr[65 * 64 + p];    // Gram rows
    sS[p]  = sr[p];              // slot rows 0..63
  }
  if (tid < 64) sSum[tid] = sr[64 * 64 + tid];
  __syncthreads();

  int o = tid & 63, part = tid >> 6;
  float m1 = 0.f, q1 = 0.f, cross = 0.f, vt2 = 0.f;
  for (int ii = 0; ii < 16; ++ii) {
    int i = part * 16 + ii;
    float vx = sVx[i * 64 + o];
    m1 = fmaf(sSum[i], vx, m1);
    float w0 = 0.f, w1 = 0.f, c0 = 0.f, c1 = 0.f;
#pragma unroll
    for (int j = 0; j < 64; j += 2) {
      float va = sVx[j * 64 + o], vb = sVx[(j + 1) * 64 + o];
      w0 = fmaf(sGx[i * 64 + j], va, w0);
      w1 = fmaf(sGx[i * 64 + j + 1], vb, w1);
      c0 = fmaf(sS[i * 64 + j], va, c0);
      c1 = fmaf(sS[i * 64 + j + 1], vb, c1);
    }
    q1 = fmaf(vx, w0 + w1, q1);
    float vt = vf[(64 + i) * 64 + o];
    vt2 = fmaf(vt, vt, vt2);
    cross = fmaf(vt, c0 + c1, cross);
  }
  sP[part][0][o] = m1;
  sP[part][1][o] = q1 + 2.f * cross + 4096.f * vt2;   // L/2 = 4096
  __syncthreads();
  if (tid < 64) {
    float m = sP[0][0][tid] + sP[1][0][tid] + sP[2][0][tid] + sP[3][0][tid];
    float q = sP[0][1][tid] + sP[1][1][tid] + sP[2][1][tid] + sP[3][1][tid];
    float D = ws[DD_OFF + b * 64 + tid] + ws[DD2_OFF + b * 64 + tid];
    ws[BNP_OFF + b * 128 + tid]      = m + 8192.f * D;
    ws[BNP_OFF + b * 128 + 64 + tid] = q + 2.f * D * m + 8192.f * D * D;
  }
}

// ---------------------------------------------------------------------------
// Phase C: out = relu(alpha*(U@V + D) + beta) via MFMA; B-fragments from
// global Vtb (L2-resident); table fragments computed in-register;
// in-block alpha/beta finalization.  2048 x 256.
__global__ __launch_bounds__(256) void k_main(const float* __restrict__ x,
                                              const float* __restrict__ ws,
                                              const float* __restrict__ bns,
                                              const float* __restrict__ bnb,
                                              float* __restrict__ out) {
  __shared__ float sD[64];
  __shared__ float sA[64];
  __shared__ float sB[64];
  __shared__ float sPp[4][64];
  __shared__ float sPq[4][64];
  int tid = threadIdx.x, w = tid >> 6, lane = tid & 63;
  int b = blockIdx.x >> 6, rg = blockIdx.x & 63;
  const u16* wsu = (const u16*)ws;

  int kb = (lane >> 4) * 8;
  const u16* vtb = wsu + VTB_OFF * 2 + b * 64 * 128;
  short8 bf[4][4];
#pragma unroll
  for (int kk = 0; kk < 4; ++kk)
#pragma unroll
    for (int ct = 0; ct < 4; ++ct)
      bf[kk][ct] = *reinterpret_cast<const short8*>(
          vtb + (ct * 16 + (lane & 15)) * 128 + kk * 32 + kb);

  {
    int o = tid & 63, g = tid >> 6;
    float pm = 0.f, pq = 0.f;
#pragma unroll
    for (int r = 0; r < 8; ++r) {
      int bb = g * 8 + r;
      pm += ws[BNP_OFF + bb * 128 + o];
      pq += ws[BNP_OFF + bb * 128 + 64 + o];
    }
    sPp[g][o] = pm;
    sPq[g][o] = pq;
  }
  if (tid < 64) sD[tid] = ws[DD_OFF + b * 64 + tid] + ws[DD2_OFF + b * 64 + tid];
  __syncthreads();
  if (tid < 64) {
    const float inv_n = 1.f / (32.f * 8192.f);
    float mean = (sPp[0][tid] + sPp[1][tid] + sPp[2][tid] + sPp[3][tid]) * inv_n;
    float ex2  = (sPq[0][tid] + sPq[1][tid] + sPq[2][tid] + sPq[3][tid]) * inv_n;
    float var = ex2 - mean * mean;
    float istd = rsqrtf(var + 1e-5f);
    float al = istd * bns[tid];
    sA[tid] = al;
    sB[tid] = bnb[tid] - mean * al;
  }
  __syncthreads();

  int rowb = (lane >> 4) * 4;
  int lbase = rg * 128 + w * 32;

#pragma unroll
  for (int rt = 0; rt < 2; ++rt) {
    int l = lbase + rt * 16 + (lane & 15);
    const float* xq = x + (b * LL + l) * 64;
    float4 u0 = *reinterpret_cast<const float4*>(xq + kb);
    float4 u1 = *reinterpret_cast<const float4*>(xq + kb + 4);
    float4 u2 = *reinterpret_cast<const float4*>(xq + 32 + kb);
    float4 u3 = *reinterpret_cast<const float4*>(xq + 32 + kb + 4);
    union { short8 s; u32 wv[4]; } A0, A1, A2, A3;
    A0.wv[0] = pk2(u0.x, u0.y); A0.wv[1] = pk2(u0.z, u0.w);
    A0.wv[2] = pk2(u1.x, u1.y); A0.wv[3] = pk2(u1.z, u1.w);
    A1.wv[0] = pk2(u2.x, u2.y); A1.wv[1] = pk2(u2.z, u2.w);
    A1.wv[2] = pk2(u3.x, u3.y); A1.wv[3] = pk2(u3.z, u3.w);
#pragma unroll
    for (int p2 = 0; p2 < 4; ++p2) {
      A2.wv[p2] = (u32)tslotj(kb + 2 * p2, l) |
                  ((u32)tslotj(kb + 2 * p2 + 1, l) << 16);
      A3.wv[p2] = (u32)tslotj(32 + kb + 2 * p2, l) |
                  ((u32)tslotj(32 + kb + 2 * p2 + 1, l) << 16);
    }

    f32x4 acc[4];
#pragma unroll
    for (int ct = 0; ct < 4; ++ct) acc[ct] = (f32x4){0.f, 0.f, 0.f, 0.f};
#pragma unroll
    for (int ct = 0; ct < 4; ++ct) {
      acc[ct] = __builtin_amdgcn_mfma_f32_16x16x32_bf16(A0.s, bf[0][ct], acc[ct], 0, 0, 0);
      acc[ct] = __builtin_amdgcn_mfma_f32_16x16x32_bf16(A1.s, bf[1][ct], acc[ct], 0, 0, 0);
      acc[ct] = __builtin_amdgcn_mfma_f32_16x16x32_bf16(A2.s, bf[2][ct], acc[ct], 0, 0, 0);
      acc[ct] = __builtin_amdgcn_mfma_f32_16x16x32_bf16(A3.s, bf[3][ct], acc[ct], 0, 0, 0);
    }
#pragma unroll
    for (int ct = 0; ct < 4; ++ct) {
      int o = ct * 16 + (lane & 15);
      float dd = sD[o], al = sA[o], be = sB[o];
#pragma unroll
      for (int r = 0; r < 4; ++r) {
        float v = acc[ct][r] + dd;
        out[(b * LL + lbase + rt * 16 + rowb + r) * 64 + o] =
            fmaxf(fmaf(v, al, be), 0.f);
      }
    }
  }
}

// ---------------------------------------------------------------------------
extern "C" void kernel_launch(void* const* d_in, const int* in_sizes, int n_in,
                              void* d_out, int out_size, void* d_ws, size_t ws_size,
                              hipStream_t stream) {
  const float* x     = (const float*)d_in[0];
  const float* t_emb = (const float*)d_in[1];
  const float* swr   = (const float*)d_in[2];
  const float* swi   = (const float*)d_in[3];
  const float* dre   = (const float*)d_in[4];
  const float* dim_  = (const float*)d_in[5];
  const float* ck    = (const float*)d_in[6];
  const float* cbias = (const float*)d_in[7];
  const float* tw    = (const float*)d_in[8];
  const float* pk    = (const float*)d_in[9];
  const float* bns   = (const float*)d_in[10];
  const float* bnb   = (const float*)d_in[11];
  float* ws  = (float*)d_ws;
  float* out = (float*)d_out;

  k_dft<<<1024, 512, 0, stream>>>(x, out);              // f16 partials in d_out
  k_red1<<<544, 256, 0, stream>>>(out);                 // -> SRED2 (in d_out)
  k_vb<<<65, 256, 0, stream>>>(t_emb, dre, dim_, pk, swr, swi,
                               ck, cbias, tw, out, ws);
  k_bn<<<32, 256, 0, stream>>>(out, ws);
  k_main<<<2048, 256, 0, stream>>>(x, ws, bns, bnb, out); // overwrites d_out
}